// Round 5
// baseline (248.565 us; speedup 1.0000x reference)
//
#include <hip/hip_runtime.h>
#include <hip/hip_fp16.h>

using i32x4  = __attribute__((ext_vector_type(4)))  int;
using i32x16 = __attribute__((ext_vector_type(16))) int;

static constexpr int M  = 4 * 2048;   // 8192 rows (B*S)
static constexpr int N  = 4096;       // OUT_F
static constexpr int K  = 4096;       // IN_F
static constexpr int BM = 256, BN = 256, BK = 64;
static constexpr int NT = K / BK;       // 64 K-tiles
static constexpr int TILE = BM * BK;    // 16384 bytes per packed int8 tile

// ---------------- pack kernels: int32 -> blocked int8 tiles in d_ws ----------
// tile layout (16 KB): [kg(4)][row(256)][16 bytes of k] -> off = kg*4096 + row*16
// wa: [M/256][NT][tile], wb: [N/256][NT][tile] (wb transposed: granule bytes walk k)

__device__ __forceinline__ unsigned pack4(i32x4 v) {
  return (unsigned)((v.x & 255) | ((v.y & 255) << 8) | ((v.z & 255) << 16) | (v.w << 24));
}

__global__ __launch_bounds__(256) void pack_x_kernel(const int* __restrict__ x,
                                                     unsigned char* __restrict__ wa) {
  unsigned g = blockIdx.x * 256 + threadIdx.x;   // dest 16B granule id, < M*K/16
  unsigned row = g & 255;
  unsigned kg  = (g >> 8) & 3;
  unsigned kt  = (g >> 10) & 63;
  unsigned br  = g >> 16;
  const int* src = x + ((size_t)(br * 256 + row) * K + kt * 64 + kg * 16);
  i32x4 v0 = *(const i32x4*)(src + 0);
  i32x4 v1 = *(const i32x4*)(src + 4);
  i32x4 v2 = *(const i32x4*)(src + 8);
  i32x4 v3 = *(const i32x4*)(src + 12);
  i32x4 d;
  d.x = (int)pack4(v0); d.y = (int)pack4(v1); d.z = (int)pack4(v2); d.w = (int)pack4(v3);
  *(i32x4*)(wa + (size_t)g * 16) = d;
}

__global__ __launch_bounds__(256) void pack_w_kernel(const int* __restrict__ w,
                                                     unsigned char* __restrict__ wb) {
  unsigned g = blockIdx.x * 256 + threadIdx.x;   // dest 16B granule id, < N*K/16
  unsigned col = g & 255;
  unsigned kg  = (g >> 8) & 3;
  unsigned kt  = (g >> 10) & 63;
  unsigned bn  = g >> 16;
  unsigned n   = bn * 256 + col;
  unsigned k0  = kt * 64 + kg * 16;
  const int* src = w + (size_t)k0 * N + n;
  i32x4 d;
#pragma unroll
  for (int j = 0; j < 4; ++j) {
    int b0 = src[(size_t)(j * 4 + 0) * N];
    int b1 = src[(size_t)(j * 4 + 1) * N];
    int b2 = src[(size_t)(j * 4 + 2) * N];
    int b3 = src[(size_t)(j * 4 + 3) * N];
    d[j] = (b0 & 255) | ((b1 & 255) << 8) | ((b2 & 255) << 16) | (b3 << 24);
  }
  *(i32x4*)(wb + (size_t)g * 16) = d;
}

// ---- GEMM: A via LDS (triple-buffer, global_load_lds), B global->VGPR ------

__device__ __forceinline__ void gload_lds16(const void* g, void* l) {
  __builtin_amdgcn_global_load_lds((const __attribute__((address_space(1))) unsigned int*)g,
                                   (__attribute__((address_space(3))) unsigned int*)l,
                                   16, 0, 0);
}

__global__ __launch_bounds__(512, 2) void gemm_i8(const unsigned char* __restrict__ wa,
                                                  const unsigned char* __restrict__ wb,
                                                  const __half* __restrict__ bias,
                                                  const float* __restrict__ alphaP,
                                                  float* __restrict__ out) {
  __shared__ __align__(16) unsigned char As[3][TILE];   // 48 KB: A only

  const int tid  = threadIdx.x;
  const int lane = tid & 63;
  const int w    = tid >> 6;            // wave 0..7
  const int wr   = w >> 2, wc = w & 3;  // 2 x 4 wave grid; wave tile 128x64
  const int l31  = lane & 31;
  const int kgl  = lane >> 5;

  // XCD swizzle for B L2-residency: each XCD (bid&7) owns exactly 2 bc panels
  // (2 x 1MB packed B < 4MB L2). br spans all 32 within the XCD's chunk.
  const int bid = blockIdx.x;
  const int i   = bid >> 3;
  const int bc  = (bid & 7) * 2 + (i >> 5);   // 0..15
  const int br  = i & 31;                     // 0..31

  const unsigned char* ga = wa + (size_t)br * NT * TILE;
  const unsigned char* gb = wb + (size_t)bc * NT * TILE;

  const int arow = wr * 128 + l31;      // A frag row base (per lane)
  const int bcol = wc * 64 + l31;       // B frag col base (per lane)

  auto stageA = [&](int buf, int t) {
    const unsigned char* at = ga + (size_t)t * TILE;
    gload_lds16(at + w * 1024 + lane * 16,        &As[buf][w * 1024]);
    gload_lds16(at + 8192 + w * 1024 + lane * 16, &As[buf][8192 + w * 1024]);
  };

  i32x4 breg[2][2][2];   // [parity][kc][ni] — all indices compile-time constant

#define LOADB(PAR, T) do {                                                   \
    const unsigned char* bt = gb + (size_t)(T) * TILE;                       \
    breg[PAR][0][0] = *(const i32x4*)(bt + (0 + kgl) * 4096 + (bcol +  0) * 16); \
    breg[PAR][0][1] = *(const i32x4*)(bt + (0 + kgl) * 4096 + (bcol + 32) * 16); \
    breg[PAR][1][0] = *(const i32x4*)(bt + (2 + kgl) * 4096 + (bcol +  0) * 16); \
    breg[PAR][1][1] = *(const i32x4*)(bt + (2 + kgl) * 4096 + (bcol + 32) * 16); \
  } while (0)

  // prologue: A(0), B(0), A(1); wait so A(0)+B(0) resident, A(1) in flight
  stageA(0, 0);
  LOADB(0, 0);
  stageA(1, 1);
  asm volatile("s_waitcnt vmcnt(2)" ::: "memory");
  __builtin_amdgcn_s_barrier();

  i32x16 acc[4][2] = {};

#define MFMA(mi, ni, AF, PAR, KC)                                            \
  acc[mi][ni] = __builtin_amdgcn_mfma_i32_32x32x32_i8(AF, breg[PAR][KC][ni], \
                                                      acc[mi][ni], 0, 0, 0)

#define STEP(T, PAR) do {                                                    \
    const unsigned char* Ab = &As[(T) % 3][0] + kgl * 4096;                  \
    i32x4 a0 = *(const i32x4*)(Ab + (arow +  0) * 16);                       \
    i32x4 a1 = *(const i32x4*)(Ab + (arow + 32) * 16);                       \
    i32x4 a2 = *(const i32x4*)(Ab + (arow + 64) * 16);                       \
    i32x4 a3 = *(const i32x4*)(Ab + (arow + 96) * 16);                       \
    if ((T) + 1 < NT) LOADB(PAR ^ 1, (T) + 1);        /* B(t+1) -> regs */   \
    if ((T) + 2 < NT) stageA(((T) + 2) % 3, (T) + 2); /* A(t+2) -> LDS */    \
    MFMA(0, 0, a0, PAR, 0); MFMA(0, 1, a0, PAR, 0);                          \
    MFMA(1, 0, a1, PAR, 0); MFMA(1, 1, a1, PAR, 0);                          \
    MFMA(2, 0, a2, PAR, 0); MFMA(2, 1, a2, PAR, 0);                          \
    MFMA(3, 0, a3, PAR, 0); MFMA(3, 1, a3, PAR, 0);                          \
    i32x4 c0 = *(const i32x4*)(Ab + 8192 + (arow +  0) * 16);                \
    i32x4 c1 = *(const i32x4*)(Ab + 8192 + (arow + 32) * 16);                \
    i32x4 c2 = *(const i32x4*)(Ab + 8192 + (arow + 64) * 16);                \
    i32x4 c3 = *(const i32x4*)(Ab + 8192 + (arow + 96) * 16);                \
    MFMA(0, 0, c0, PAR, 1); MFMA(0, 1, c0, PAR, 1);                          \
    MFMA(1, 0, c1, PAR, 1); MFMA(1, 1, c1, PAR, 1);                          \
    MFMA(2, 0, c2, PAR, 1); MFMA(2, 1, c2, PAR, 1);                          \
    MFMA(3, 0, c3, PAR, 1); MFMA(3, 1, c3, PAR, 1);                          \
    /* A(t+1)+B(t+1) done, A(t+2) stays in flight; never vmcnt(0) mid-loop */\
    if ((T) + 2 < NT)      asm volatile("s_waitcnt vmcnt(2)" ::: "memory");  \
    else if ((T) + 1 < NT) asm volatile("s_waitcnt vmcnt(0)" ::: "memory");  \
    if ((T) + 1 < NT) __builtin_amdgcn_s_barrier();                          \
  } while (0)

  for (int t = 0; t < NT; t += 2) {   // NT even; parity keeps breg indices constant
    STEP(t, 0);
    STEP(t + 1, 1);
  }

  // epilogue: C/D layout col=lane&31, row=(r&3)+8*(r>>2)+4*(lane>>5)
  const float alpha = *alphaP;
  const int row0 = br * 256 + wr * 128 + 4 * kgl;
  const int col0 = bc * 256 + wc * 64 + l31;
#pragma unroll
  for (int ni = 0; ni < 2; ++ni) {
    const int col = col0 + ni * 32;
    const float bf = __half2float(bias[col]);
#pragma unroll
    for (int mi = 0; mi < 4; ++mi) {
#pragma unroll
      for (int r = 0; r < 16; ++r) {
        const int row = row0 + mi * 32 + (r & 3) + 8 * (r >> 2);
        out[(size_t)row * N + col] = ((float)acc[mi][ni][r] + bf) * alpha;
      }
    }
  }
#undef STEP
#undef MFMA
#undef LOADB
}

extern "C" void kernel_launch(void* const* d_in, const int* in_sizes, int n_in,
                              void* d_out, int out_size, void* d_ws, size_t ws_size,
                              hipStream_t stream) {
  const int*    x     = (const int*)d_in[0];
  const int*    wgt   = (const int*)d_in[1];
  const __half* bias  = (const __half*)d_in[2];
  const float*  alpha = (const float*)d_in[3];
  float*        out   = (float*)d_out;

  // workspace: packed A (32 MB) + packed B (16 MB) = 48 MB
  unsigned char* wa = (unsigned char*)d_ws;
  unsigned char* wb = wa + (size_t)M * K;

  pack_x_kernel<<<(M * (size_t)K / 16) / 256, 256, 0, stream>>>(x, wa);
  pack_w_kernel<<<(N * (size_t)K / 16) / 256, 256, 0, stream>>>(wgt, wb);

  dim3 grid((M / BM) * (N / BN));   // 512 blocks
  gemm_i8<<<grid, 512, 0, stream>>>(wa, wb, bias, alpha, out);
}